// Round 4
// baseline (325.405 us; speedup 1.0000x reference)
//
#include <hip/hip_runtime.h>
#include <hip/hip_fp16.h>
#include <math.h>

#define NN 100000
#define NE 1600000
#define FIN 50
#define NC 16
#define TILE_NODES 32

#define NPB 128                       // nodes per bucket
#define NB  ((NN + NPB - 1) / NPB)    // 782 buckets
#define NBLK_PART 256
#define EPB ((NE + NBLK_PART - 1) / NBLK_PART)   // 6250 edges / partition block

// ---------------------------------------------------------------------------
// Kernel 1: y_l = x @ W_l^T (f16, ws), self = x @ W_r^T (f32, d_out high half)
// ---------------------------------------------------------------------------
__global__ __launch_bounds__(256) void lin_kernel(
    const float* __restrict__ x,
    const float* __restrict__ W_l,
    const float* __restrict__ W_r,
    __half2* __restrict__ y_l,        // [NN*8]
    float* __restrict__ self_out)     // [NN*NC]
{
    __shared__ float sWl[NC * FIN];
    __shared__ float sWr[NC * FIN];
    __shared__ float sx[TILE_NODES * FIN];

    const int tid = threadIdx.x;
    for (int i = tid; i < NC * FIN; i += 256) {
        sWl[i] = W_l[i];
        sWr[i] = W_r[i];
    }

    const int ntiles = (NN + TILE_NODES - 1) / TILE_NODES;
    const int ln = tid >> 3;
    const int cp = tid & 7;

    for (int tile = blockIdx.x; tile < ntiles; tile += gridDim.x) {
        __syncthreads();
        const int node0 = tile * TILE_NODES;
        for (int i = tid; i < TILE_NODES * FIN; i += 256) {
            int n = node0 + i / FIN;
            sx[i] = (n < NN) ? x[n * FIN + (i % FIN)] : 0.0f;
        }
        __syncthreads();

        const int n = node0 + ln;
        if (n >= NN) continue;

        const float* xr = &sx[ln * FIN];
        const float* w0 = &sWl[(2 * cp) * FIN];
        const float* w1 = w0 + FIN;
        const float* u0 = &sWr[(2 * cp) * FIN];
        const float* u1 = u0 + FIN;

        float a0 = 0.f, a1 = 0.f, r0 = 0.f, r1 = 0.f;
#pragma unroll
        for (int k = 0; k < FIN; ++k) {
            float xv = xr[k];
            a0 = fmaf(xv, w0[k], a0);
            a1 = fmaf(xv, w1[k], a1);
            r0 = fmaf(xv, u0[k], r0);
            r1 = fmaf(xv, u1[k], r1);
        }
        y_l[n * 8 + cp] = __floats2half2_rn(a0, a1);
        ((float2*)self_out)[n * 8 + cp] = make_float2(r0, r1);
    }
}

// ---------------------------------------------------------------------------
// Kernel 2: per-bucket histogram (LDS pre-agg; global counters strided x16
// so each lives on its own cache line — low contention).
// ---------------------------------------------------------------------------
__global__ __launch_bounds__(256) void hist_kernel(
    const int* __restrict__ ei, int* __restrict__ counts_s)
{
    __shared__ int h[NB];
    for (int i = threadIdx.x; i < NB; i += 256) h[i] = 0;
    __syncthreads();
    int e0 = blockIdx.x * EPB;
    int e1 = min(e0 + EPB, NE);
    for (int e = e0 + threadIdx.x; e < e1; e += 256)
        atomicAdd(&h[ei[NE + e] >> 7], 1);
    __syncthreads();
    for (int b = threadIdx.x; b < NB; b += 256)
        if (h[b]) atomicAdd(&counts_s[b * 16], h[b]);
}

// ---------------------------------------------------------------------------
// Kernel 3: exclusive scan of 782 bucket counts (single block).
// counts_s[b*16]   = count (kept)
// counts_s[b*16+1] = exclusive base (for agg kernel)
// gcur_s[b*16]     = exclusive base (mutable cursor for place kernel)
// ---------------------------------------------------------------------------
__global__ __launch_bounds__(1024) void scan_kernel(
    int* __restrict__ counts_s, int* __restrict__ gcur_s)
{
    __shared__ int buf[1024];
    int tid = threadIdx.x;
    int v = (tid < NB) ? counts_s[tid * 16] : 0;
    buf[tid] = v;
    __syncthreads();
    for (int off = 1; off < 1024; off <<= 1) {
        int t = (tid >= off) ? buf[tid - off] : 0;
        __syncthreads();
        buf[tid] += t;
        __syncthreads();
    }
    if (tid < NB) {
        int excl = buf[tid] - v;
        counts_s[tid * 16 + 1] = excl;
        gcur_s[tid * 16] = excl;
    }
}

// ---------------------------------------------------------------------------
// Kernel 4: placement. Each block: local hist -> reserve one contiguous chunk
// per bucket (1 global atomic per (block,bucket)) -> write packed (src,tl)
// u32 per edge into its bucket chunk. Chunks are contiguous dwords, so lines
// are (mostly) fully covered — unlike the 4B-in-64B random scatter of R2.
// ---------------------------------------------------------------------------
__global__ __launch_bounds__(256) void place_kernel(
    const int* __restrict__ ei, int* __restrict__ gcur_s,
    unsigned int* __restrict__ buf)
{
    __shared__ int h[NB];
    __shared__ int cur[NB];
    for (int i = threadIdx.x; i < NB; i += 256) h[i] = 0;
    __syncthreads();
    int e0 = blockIdx.x * EPB;
    int e1 = min(e0 + EPB, NE);
    for (int e = e0 + threadIdx.x; e < e1; e += 256)
        atomicAdd(&h[ei[NE + e] >> 7], 1);
    __syncthreads();
    for (int b = threadIdx.x; b < NB; b += 256)
        cur[b] = h[b] ? atomicAdd(&gcur_s[b * 16], h[b]) : 0;
    __syncthreads();
    for (int e = e0 + threadIdx.x; e < e1; e += 256) {
        int s = ei[e];
        int t = ei[NE + e];
        int b = t >> 7;
        int pos = atomicAdd(&cur[b], 1);
        buf[pos] = (unsigned)s | ((unsigned)(t & 127) << 17);
    }
}

// ---------------------------------------------------------------------------
// Kernel 5: per-bucket LDS aggregation + fused epilogue.
// Class-major LDS layout agg[c*NPB+tl]: bank = tl%32, random tl -> ~2-way.
// Epilogue (tid < NPB): mean + bias + self + log_softmax, vector stores.
// ---------------------------------------------------------------------------
__global__ __launch_bounds__(256) void agg_kernel(
    const int* __restrict__ counts_s,
    const unsigned int* __restrict__ buf,
    const __half2* __restrict__ y_l,
    const float* __restrict__ b_l,
    float* __restrict__ logp,
    float* __restrict__ outv)   // self (f32) on entry, final out on exit
{
    __shared__ float agg[NC * NPB];   // 8 KB
    __shared__ int   deg[NPB];
    __shared__ float sb[NC];

    int tid = threadIdx.x;
    for (int i = tid; i < NC * NPB; i += 256) agg[i] = 0.0f;
    if (tid < NPB) deg[tid] = 0;
    if (tid < NC) sb[tid] = b_l[tid];
    __syncthreads();

    const int b     = blockIdx.x;
    const int cnt   = counts_s[b * 16];
    const int start = counts_s[b * 16 + 1];

    for (int i = tid; i < cnt; i += 256) {
        unsigned v = buf[start + i];
        int s  = v & 0x1FFFF;
        int tl = v >> 17;
        const int4* p = (const int4*)(y_l + (size_t)s * 8);
        int4 q0 = p[0], q1 = p[1];
        int qa[8] = {q0.x, q0.y, q0.z, q0.w, q1.x, q1.y, q1.z, q1.w};
#pragma unroll
        for (int j = 0; j < 8; ++j) {
            __half2 hv = *(__half2*)&qa[j];
            float2 f = __half22float2(hv);
            atomicAdd(&agg[(2 * j) * NPB + tl],     f.x);
            atomicAdd(&agg[(2 * j + 1) * NPB + tl], f.y);
        }
        atomicAdd(&deg[tl], 1);
    }
    __syncthreads();

    if (tid >= NPB) return;
    int n = b * NPB + tid;
    if (n >= NN) return;

    float sv[NC];
    float4* svv = (float4*)sv;
    const float4* selfp = (const float4*)(outv + (size_t)n * NC);
#pragma unroll
    for (int j = 0; j < 4; ++j) svv[j] = selfp[j];

    float inv = 1.0f / fmaxf((float)deg[tid], 1.0f);
    float vals[NC];
    float m = -3.0e38f;
#pragma unroll
    for (int c = 0; c < NC; ++c) {
        float val = agg[c * NPB + tid] * inv + sb[c] + sv[c];
        vals[c] = val;
        m = fmaxf(m, val);
    }
    float es = 0.0f;
#pragma unroll
    for (int c = 0; c < NC; ++c) es += expf(vals[c] - m);
    float lse = m + logf(es);

    float4* lp = (float4*)(logp + (size_t)n * NC);
    float4* op = (float4*)(outv + (size_t)n * NC);
#pragma unroll
    for (int j = 0; j < 4; ++j) {
        float4 o = make_float4(vals[4 * j], vals[4 * j + 1],
                               vals[4 * j + 2], vals[4 * j + 3]);
        op[j] = o;
        lp[j] = make_float4(o.x - lse, o.y - lse, o.z - lse, o.w - lse);
    }
}

extern "C" void kernel_launch(void* const* d_in, const int* in_sizes, int n_in,
                              void* d_out, int out_size, void* d_ws, size_t ws_size,
                              hipStream_t stream) {
    const float* x   = (const float*)d_in[0];
    const int*   ei  = (const int*)d_in[1];
    const float* W_l = (const float*)d_in[2];
    const float* b_l = (const float*)d_in[3];
    const float* W_r = (const float*)d_in[4];

    float* logp = (float*)d_out;                    // [NN*NC]
    float* outv = (float*)d_out + (size_t)NN * NC;  // [NN*NC], self scratch

    // ws: y_l half2[NN*8] (3.2MB) | buf u32[NE] (6.4MB) | counts_s[NB*16] | gcur_s[NB*16]
    __half2* y_l      = (__half2*)d_ws;
    unsigned* buf     = (unsigned*)(y_l + (size_t)NN * 8);
    int* counts_s     = (int*)(buf + NE);
    int* gcur_s       = counts_s + NB * 16;

    hipMemsetAsync(counts_s, 0, (size_t)NB * 16 * sizeof(int), stream);

    lin_kernel<<<1024, 256, 0, stream>>>(x, W_l, W_r, y_l, outv);
    hist_kernel<<<NBLK_PART, 256, 0, stream>>>(ei, counts_s);
    scan_kernel<<<1, 1024, 0, stream>>>(counts_s, gcur_s);
    place_kernel<<<NBLK_PART, 256, 0, stream>>>(ei, gcur_s, buf);
    agg_kernel<<<NB, 256, 0, stream>>>(counts_s, buf, y_l, b_l, logp, outv);
}

// Round 5
// 317.805 us; speedup vs baseline: 1.0239x; 1.0239x over previous
//
#include <hip/hip_runtime.h>
#include <hip/hip_fp16.h>
#include <math.h>

#define NN 100000
#define NE 1600000
#define FIN 50
#define NC 16
#define TILE_NODES 32

#define NPB 64                        // nodes per bucket (multiple of 32!)
#define NB  ((NN + NPB - 1) / NPB)    // 1563 buckets
#define NBLK_PART 192
#define EPB ((NE + NBLK_PART - 1) / NBLK_PART)   // 8334 edges / partition block

// ---------------------------------------------------------------------------
// Kernel 1: y_l = x @ W_l^T (f16, ws), self = x @ W_r^T (f32, d_out high half)
// ---------------------------------------------------------------------------
__global__ __launch_bounds__(256) void lin_kernel(
    const float* __restrict__ x,
    const float* __restrict__ W_l,
    const float* __restrict__ W_r,
    __half2* __restrict__ y_l,        // [NN*8]
    float* __restrict__ self_out)     // [NN*NC]
{
    __shared__ float sWl[NC * FIN];
    __shared__ float sWr[NC * FIN];
    __shared__ float sx[TILE_NODES * FIN];

    const int tid = threadIdx.x;
    for (int i = tid; i < NC * FIN; i += 256) {
        sWl[i] = W_l[i];
        sWr[i] = W_r[i];
    }

    const int ntiles = (NN + TILE_NODES - 1) / TILE_NODES;
    const int ln = tid >> 3;
    const int cp = tid & 7;

    for (int tile = blockIdx.x; tile < ntiles; tile += gridDim.x) {
        __syncthreads();
        const int node0 = tile * TILE_NODES;
        for (int i = tid; i < TILE_NODES * FIN; i += 256) {
            int n = node0 + i / FIN;
            sx[i] = (n < NN) ? x[n * FIN + (i % FIN)] : 0.0f;
        }
        __syncthreads();

        const int n = node0 + ln;
        if (n >= NN) continue;

        const float* xr = &sx[ln * FIN];
        const float* w0 = &sWl[(2 * cp) * FIN];
        const float* w1 = w0 + FIN;
        const float* u0 = &sWr[(2 * cp) * FIN];
        const float* u1 = u0 + FIN;

        float a0 = 0.f, a1 = 0.f, r0 = 0.f, r1 = 0.f;
#pragma unroll
        for (int k = 0; k < FIN; ++k) {
            float xv = xr[k];
            a0 = fmaf(xv, w0[k], a0);
            a1 = fmaf(xv, w1[k], a1);
            r0 = fmaf(xv, u0[k], r0);
            r1 = fmaf(xv, u1[k], r1);
        }
        y_l[n * 8 + cp] = __floats2half2_rn(a0, a1);
        ((float2*)self_out)[n * 8 + cp] = make_float2(r0, r1);
    }
}

// ---------------------------------------------------------------------------
// Kernel 2: per-bucket histogram (LDS pre-agg; global counters strided x16)
// ---------------------------------------------------------------------------
__global__ __launch_bounds__(256) void hist_kernel(
    const int* __restrict__ ei, int* __restrict__ counts_s)
{
    __shared__ int h[NB];
    for (int i = threadIdx.x; i < NB; i += 256) h[i] = 0;
    __syncthreads();
    int e0 = blockIdx.x * EPB;
    int e1 = min(e0 + EPB, NE);
    for (int e = e0 + threadIdx.x; e < e1; e += 256)
        atomicAdd(&h[ei[NE + e] >> 6], 1);
    __syncthreads();
    for (int b = threadIdx.x; b < NB; b += 256)
        if (h[b]) atomicAdd(&counts_s[b * 16], h[b]);
}

// ---------------------------------------------------------------------------
// Kernel 3: exclusive scan of NB=1563 bucket counts, 2 elements per thread.
// counts_s[b*16]=count, counts_s[b*16+1]=exclusive base, gcur_s[b*16]=cursor
// ---------------------------------------------------------------------------
__global__ __launch_bounds__(1024) void scan_kernel(
    int* __restrict__ counts_s, int* __restrict__ gcur_s)
{
    __shared__ int buf[1024];
    int tid = threadIdx.x;
    int i0 = 2 * tid, i1 = 2 * tid + 1;
    int e0 = (i0 < NB) ? counts_s[i0 * 16] : 0;
    int e1 = (i1 < NB) ? counts_s[i1 * 16] : 0;
    int pair = e0 + e1;
    buf[tid] = pair;
    __syncthreads();
    for (int off = 1; off < 1024; off <<= 1) {
        int t = (tid >= off) ? buf[tid - off] : 0;
        __syncthreads();
        buf[tid] += t;
        __syncthreads();
    }
    int excl = buf[tid] - pair;
    if (i0 < NB) { counts_s[i0 * 16 + 1] = excl;      gcur_s[i0 * 16] = excl; }
    if (i1 < NB) { counts_s[i1 * 16 + 1] = excl + e0; gcur_s[i1 * 16] = excl + e0; }
}

// ---------------------------------------------------------------------------
// Kernel 4: placement into per-bucket contiguous chunks (packed (src,tl) u32)
// ---------------------------------------------------------------------------
__global__ __launch_bounds__(256) void place_kernel(
    const int* __restrict__ ei, int* __restrict__ gcur_s,
    unsigned int* __restrict__ buf)
{
    __shared__ int h[NB];
    __shared__ int cur[NB];
    for (int i = threadIdx.x; i < NB; i += 256) h[i] = 0;
    __syncthreads();
    int e0 = blockIdx.x * EPB;
    int e1 = min(e0 + EPB, NE);
    for (int e = e0 + threadIdx.x; e < e1; e += 256)
        atomicAdd(&h[ei[NE + e] >> 6], 1);
    __syncthreads();
    for (int b = threadIdx.x; b < NB; b += 256)
        cur[b] = h[b] ? atomicAdd(&gcur_s[b * 16], h[b]) : 0;
    __syncthreads();
    for (int e = e0 + threadIdx.x; e < e1; e += 256) {
        int s = ei[e];
        int t = ei[NE + e];
        int b = t >> 6;
        int pos = atomicAdd(&cur[b], 1);
        buf[pos] = (unsigned)s | ((unsigned)(t & 63) << 17);
    }
}

// ---------------------------------------------------------------------------
// Kernel 5: per-bucket LDS aggregation (native ds_add_f32 via unsafeAtomicAdd,
// no local arrays -> no scratch) + fused mean/bias/self/log_softmax epilogue.
// Class-major LDS agg[c*NPB+tl]: per-instruction banks = tl%32 (NPB%32==0),
// random tl -> ~2-way conflicts (free).
// ---------------------------------------------------------------------------
__global__ __launch_bounds__(256) void agg_kernel(
    const int* __restrict__ counts_s,
    const unsigned int* __restrict__ buf,
    const __half2* __restrict__ y_l,
    const float* __restrict__ b_l,
    float* __restrict__ logp,
    float* __restrict__ outv)   // self (f32) on entry, final out on exit
{
    __shared__ float agg[NC * NPB];   // 4 KB
    __shared__ int   deg[NPB];
    __shared__ float sb[NC];

    int tid = threadIdx.x;
    for (int i = tid; i < NC * NPB; i += 256) agg[i] = 0.0f;
    if (tid < NPB) deg[tid] = 0;
    if (tid < NC) sb[tid] = b_l[tid];
    __syncthreads();

    const int b     = blockIdx.x;
    const int cnt   = counts_s[b * 16];
    const int start = counts_s[b * 16 + 1];
    const uint4* yv = (const uint4*)y_l;

    for (int i = tid; i < cnt; i += 256) {
        unsigned v = buf[start + i];
        int s  = v & 0x1FFFF;
        int tl = v >> 17;
        uint4 q0 = yv[s * 2];
        uint4 q1 = yv[s * 2 + 1];
        float* base = &agg[tl];
        float2 f;
        f = __half22float2(__builtin_bit_cast(__half2, q0.x));
        unsafeAtomicAdd(base + 0 * NPB, f.x);  unsafeAtomicAdd(base + 1 * NPB, f.y);
        f = __half22float2(__builtin_bit_cast(__half2, q0.y));
        unsafeAtomicAdd(base + 2 * NPB, f.x);  unsafeAtomicAdd(base + 3 * NPB, f.y);
        f = __half22float2(__builtin_bit_cast(__half2, q0.z));
        unsafeAtomicAdd(base + 4 * NPB, f.x);  unsafeAtomicAdd(base + 5 * NPB, f.y);
        f = __half22float2(__builtin_bit_cast(__half2, q0.w));
        unsafeAtomicAdd(base + 6 * NPB, f.x);  unsafeAtomicAdd(base + 7 * NPB, f.y);
        f = __half22float2(__builtin_bit_cast(__half2, q1.x));
        unsafeAtomicAdd(base + 8 * NPB, f.x);  unsafeAtomicAdd(base + 9 * NPB, f.y);
        f = __half22float2(__builtin_bit_cast(__half2, q1.y));
        unsafeAtomicAdd(base + 10 * NPB, f.x); unsafeAtomicAdd(base + 11 * NPB, f.y);
        f = __half22float2(__builtin_bit_cast(__half2, q1.z));
        unsafeAtomicAdd(base + 12 * NPB, f.x); unsafeAtomicAdd(base + 13 * NPB, f.y);
        f = __half22float2(__builtin_bit_cast(__half2, q1.w));
        unsafeAtomicAdd(base + 14 * NPB, f.x); unsafeAtomicAdd(base + 15 * NPB, f.y);
        atomicAdd(&deg[tl], 1);
    }
    __syncthreads();

    if (tid >= NPB) return;
    int n = b * NPB + tid;
    if (n >= NN) return;

    const float4* selfp = (const float4*)(outv + (size_t)n * NC);
    float4 s0 = selfp[0], s1 = selfp[1], s2 = selfp[2], s3 = selfp[3];

    float inv = 1.0f / fmaxf((float)deg[tid], 1.0f);
    float v0  = agg[ 0 * NPB + tid] * inv + sb[ 0] + s0.x;
    float v1  = agg[ 1 * NPB + tid] * inv + sb[ 1] + s0.y;
    float v2  = agg[ 2 * NPB + tid] * inv + sb[ 2] + s0.z;
    float v3  = agg[ 3 * NPB + tid] * inv + sb[ 3] + s0.w;
    float v4  = agg[ 4 * NPB + tid] * inv + sb[ 4] + s1.x;
    float v5  = agg[ 5 * NPB + tid] * inv + sb[ 5] + s1.y;
    float v6  = agg[ 6 * NPB + tid] * inv + sb[ 6] + s1.z;
    float v7  = agg[ 7 * NPB + tid] * inv + sb[ 7] + s1.w;
    float v8  = agg[ 8 * NPB + tid] * inv + sb[ 8] + s2.x;
    float v9  = agg[ 9 * NPB + tid] * inv + sb[ 9] + s2.y;
    float v10 = agg[10 * NPB + tid] * inv + sb[10] + s2.z;
    float v11 = agg[11 * NPB + tid] * inv + sb[11] + s2.w;
    float v12 = agg[12 * NPB + tid] * inv + sb[12] + s3.x;
    float v13 = agg[13 * NPB + tid] * inv + sb[13] + s3.y;
    float v14 = agg[14 * NPB + tid] * inv + sb[14] + s3.z;
    float v15 = agg[15 * NPB + tid] * inv + sb[15] + s3.w;

    float m = fmaxf(fmaxf(fmaxf(fmaxf(v0, v1), fmaxf(v2, v3)),
                          fmaxf(fmaxf(v4, v5), fmaxf(v6, v7))),
                    fmaxf(fmaxf(fmaxf(v8, v9), fmaxf(v10, v11)),
                          fmaxf(fmaxf(v12, v13), fmaxf(v14, v15))));
    float es = expf(v0 - m)  + expf(v1 - m)  + expf(v2 - m)  + expf(v3 - m)
             + expf(v4 - m)  + expf(v5 - m)  + expf(v6 - m)  + expf(v7 - m)
             + expf(v8 - m)  + expf(v9 - m)  + expf(v10 - m) + expf(v11 - m)
             + expf(v12 - m) + expf(v13 - m) + expf(v14 - m) + expf(v15 - m);
    float lse = m + logf(es);

    float4* op = (float4*)(outv + (size_t)n * NC);
    float4* lp = (float4*)(logp + (size_t)n * NC);
    op[0] = make_float4(v0, v1, v2, v3);
    op[1] = make_float4(v4, v5, v6, v7);
    op[2] = make_float4(v8, v9, v10, v11);
    op[3] = make_float4(v12, v13, v14, v15);
    lp[0] = make_float4(v0 - lse, v1 - lse, v2 - lse, v3 - lse);
    lp[1] = make_float4(v4 - lse, v5 - lse, v6 - lse, v7 - lse);
    lp[2] = make_float4(v8 - lse, v9 - lse, v10 - lse, v11 - lse);
    lp[3] = make_float4(v12 - lse, v13 - lse, v14 - lse, v15 - lse);
}

extern "C" void kernel_launch(void* const* d_in, const int* in_sizes, int n_in,
                              void* d_out, int out_size, void* d_ws, size_t ws_size,
                              hipStream_t stream) {
    const float* x   = (const float*)d_in[0];
    const int*   ei  = (const int*)d_in[1];
    const float* W_l = (const float*)d_in[2];
    const float* b_l = (const float*)d_in[3];
    const float* W_r = (const float*)d_in[4];

    float* logp = (float*)d_out;                    // [NN*NC]
    float* outv = (float*)d_out + (size_t)NN * NC;  // [NN*NC], self scratch

    // ws: y_l half2[NN*8] (3.2MB) | buf u32[NE] (6.4MB) | counts_s[NB*16] | gcur_s[NB*16]
    __half2* y_l  = (__half2*)d_ws;
    unsigned* buf = (unsigned*)(y_l + (size_t)NN * 8);
    int* counts_s = (int*)(buf + NE);
    int* gcur_s   = counts_s + NB * 16;

    hipMemsetAsync(counts_s, 0, (size_t)NB * 16 * sizeof(int), stream);

    lin_kernel<<<1024, 256, 0, stream>>>(x, W_l, W_r, y_l, outv);
    hist_kernel<<<NBLK_PART, 256, 0, stream>>>(ei, counts_s);
    scan_kernel<<<1, 1024, 0, stream>>>(counts_s, gcur_s);
    place_kernel<<<NBLK_PART, 256, 0, stream>>>(ei, gcur_s, buf);
    agg_kernel<<<NB, 256, 0, stream>>>(counts_s, buf, y_l, b_l, logp, outv);
}

// Round 6
// 183.402 us; speedup vs baseline: 1.7743x; 1.7328x over previous
//
#include <hip/hip_runtime.h>
#include <hip/hip_fp16.h>
#include <math.h>

#define NN 100000
#define NE 1600000
#define FIN 50
#define NC 16
#define TILE_NODES 32

#define NPB 64                        // nodes per bucket
#define NB  ((NN + NPB - 1) / NPB)    // 1563 buckets
#define NBLK_PART 192
#define EPB ((NE + NBLK_PART - 1) / NBLK_PART)   // edges per partition block
#define SLCAP 2048                    // slist capacity (mean 1024, sd 32 -> safe)

// ---------------------------------------------------------------------------
// Kernel 1: y_l = x @ W_l^T (f16, ws), self = x @ W_r^T (f32, d_out high half)
// ---------------------------------------------------------------------------
__global__ __launch_bounds__(256) void lin_kernel(
    const float* __restrict__ x,
    const float* __restrict__ W_l,
    const float* __restrict__ W_r,
    __half2* __restrict__ y_l,        // [NN*8]
    float* __restrict__ self_out)     // [NN*NC]
{
    __shared__ float sWl[NC * FIN];
    __shared__ float sWr[NC * FIN];
    __shared__ float sx[TILE_NODES * FIN];

    const int tid = threadIdx.x;
    for (int i = tid; i < NC * FIN; i += 256) {
        sWl[i] = W_l[i];
        sWr[i] = W_r[i];
    }

    const int ntiles = (NN + TILE_NODES - 1) / TILE_NODES;
    const int ln = tid >> 3;
    const int cp = tid & 7;

    for (int tile = blockIdx.x; tile < ntiles; tile += gridDim.x) {
        __syncthreads();
        const int node0 = tile * TILE_NODES;
        for (int i = tid; i < TILE_NODES * FIN; i += 256) {
            int n = node0 + i / FIN;
            sx[i] = (n < NN) ? x[n * FIN + (i % FIN)] : 0.0f;
        }
        __syncthreads();

        const int n = node0 + ln;
        if (n >= NN) continue;

        const float* xr = &sx[ln * FIN];
        const float* w0 = &sWl[(2 * cp) * FIN];
        const float* w1 = w0 + FIN;
        const float* u0 = &sWr[(2 * cp) * FIN];
        const float* u1 = u0 + FIN;

        float a0 = 0.f, a1 = 0.f, r0 = 0.f, r1 = 0.f;
#pragma unroll
        for (int k = 0; k < FIN; ++k) {
            float xv = xr[k];
            a0 = fmaf(xv, w0[k], a0);
            a1 = fmaf(xv, w1[k], a1);
            r0 = fmaf(xv, u0[k], r0);
            r1 = fmaf(xv, u1[k], r1);
        }
        y_l[n * 8 + cp] = __floats2half2_rn(a0, a1);
        ((float2*)self_out)[n * 8 + cp] = make_float2(r0, r1);
    }
}

// ---------------------------------------------------------------------------
// Kernel 2: per-bucket histogram (LDS pre-agg; global counters strided x16)
// ---------------------------------------------------------------------------
__global__ __launch_bounds__(256) void hist_kernel(
    const int* __restrict__ ei, int* __restrict__ counts_s)
{
    __shared__ int h[NB];
    for (int i = threadIdx.x; i < NB; i += 256) h[i] = 0;
    __syncthreads();
    int e0 = blockIdx.x * EPB;
    int e1 = min(e0 + EPB, NE);
    for (int e = e0 + threadIdx.x; e < e1; e += 256)
        atomicAdd(&h[ei[NE + e] >> 6], 1);
    __syncthreads();
    for (int b = threadIdx.x; b < NB; b += 256)
        if (h[b]) atomicAdd(&counts_s[b * 16], h[b]);
}

// ---------------------------------------------------------------------------
// Kernel 3: exclusive scan of NB bucket counts, 2 elements per thread.
// counts_s[b*16]=count, counts_s[b*16+1]=exclusive base, gcur_s[b*16]=cursor
// ---------------------------------------------------------------------------
__global__ __launch_bounds__(1024) void scan_kernel(
    int* __restrict__ counts_s, int* __restrict__ gcur_s)
{
    __shared__ int buf[1024];
    int tid = threadIdx.x;
    int i0 = 2 * tid, i1 = 2 * tid + 1;
    int e0 = (i0 < NB) ? counts_s[i0 * 16] : 0;
    int e1 = (i1 < NB) ? counts_s[i1 * 16] : 0;
    int pair = e0 + e1;
    buf[tid] = pair;
    __syncthreads();
    for (int off = 1; off < 1024; off <<= 1) {
        int t = (tid >= off) ? buf[tid - off] : 0;
        __syncthreads();
        buf[tid] += t;
        __syncthreads();
    }
    int excl = buf[tid] - pair;
    if (i0 < NB) { counts_s[i0 * 16 + 1] = excl;      gcur_s[i0 * 16] = excl; }
    if (i1 < NB) { counts_s[i1 * 16 + 1] = excl + e0; gcur_s[i1 * 16] = excl + e0; }
}

// ---------------------------------------------------------------------------
// Kernel 4: placement into per-bucket contiguous chunks: packed (tl<<17 | src)
// ---------------------------------------------------------------------------
__global__ __launch_bounds__(256) void place_kernel(
    const int* __restrict__ ei, int* __restrict__ gcur_s,
    unsigned int* __restrict__ buf)
{
    __shared__ int h[NB];
    __shared__ int cur[NB];
    for (int i = threadIdx.x; i < NB; i += 256) h[i] = 0;
    __syncthreads();
    int e0 = blockIdx.x * EPB;
    int e1 = min(e0 + EPB, NE);
    for (int e = e0 + threadIdx.x; e < e1; e += 256)
        atomicAdd(&h[ei[NE + e] >> 6], 1);
    __syncthreads();
    for (int b = threadIdx.x; b < NB; b += 256)
        cur[b] = h[b] ? atomicAdd(&gcur_s[b * 16], h[b]) : 0;
    __syncthreads();
    for (int e = e0 + threadIdx.x; e < e1; e += 256) {
        int s = ei[e];
        int t = ei[NE + e];
        int b = t >> 6;
        int pos = atomicAdd(&cur[b], 1);
        buf[pos] = (unsigned)s | ((unsigned)(t & 63) << 17);
    }
}

// ---------------------------------------------------------------------------
// Kernel 5: per-bucket counting sort in LDS (3 lane-ops/edge, int atomics
// only) + contention-free register segment-reduce + fused epilogue.
// Thread mapping pass 4/5: tid = tl*4 + q; quad lanes q=0..3 cover the 16
// classes via uint2 (8B) loads -> 32B contiguous per edge, coalesced.
// ---------------------------------------------------------------------------
__global__ __launch_bounds__(256) void agg_kernel(
    const int* __restrict__ counts_s,
    const unsigned int* __restrict__ buf,
    const uint2* __restrict__ y2,     // y_l as uint2[NN*4]
    const float* __restrict__ b_l,
    float* __restrict__ logp,
    float* __restrict__ outv)         // self (f32) on entry, final out on exit
{
    __shared__ unsigned slist[SLCAP];
    __shared__ int lcnt[NPB];
    __shared__ int scur[NPB];
    __shared__ int sstart[NPB];
    __shared__ float sb[NC];

    const int tid = threadIdx.x;
    if (tid < NPB) lcnt[tid] = 0;
    if (tid < NC) sb[tid] = b_l[tid];
    __syncthreads();

    const int b      = blockIdx.x;
    int cnt          = counts_s[b * 16];
    const int gstart = counts_s[b * 16 + 1];
    if (cnt > SLCAP) cnt = SLCAP;   // statistically impossible; memory guard

    // pass 1: per-local-node counts (1 LDS int atomic per edge)
    for (int i = tid; i < cnt; i += 256)
        atomicAdd(&lcnt[buf[gstart + i] >> 17], 1);
    __syncthreads();

    // pass 2: 64-wide exclusive scan in the first wave
    if (tid < 64) {
        int own = lcnt[tid];
        int incl = own;
#pragma unroll
        for (int off = 1; off < 64; off <<= 1) {
            int t = __shfl_up(incl, off, 64);
            if (tid >= off) incl += t;
        }
        sstart[tid] = incl - own;
        scur[tid]   = incl - own;
    }
    __syncthreads();

    // pass 3: scatter src ids into sorted slots (1 atomic + 1 write per edge)
    for (int i = tid; i < cnt; i += 256) {
        unsigned v = buf[gstart + i];
        int tl = v >> 17;
        int pos = atomicAdd(&scur[tl], 1);
        slist[pos] = v & 0x1FFFF;
    }
    __syncthreads();

    // pass 4: segment reduce, registers only
    const int tl = tid >> 2;
    const int q  = tid & 3;
    const int n  = b * NPB + tl;
    if (n >= NN) return;

    const int seg0 = sstart[tl];
    const int deg  = lcnt[tl];
    const int seg1 = seg0 + deg;

    float a0 = 0.f, a1 = 0.f, a2 = 0.f, a3 = 0.f;
    int i = seg0;
    for (; i + 2 <= seg1; i += 2) {
        int sA = slist[i];
        int sB = slist[i + 1];
        uint2 qa = y2[sA * 4 + q];
        uint2 qb = y2[sB * 4 + q];
        float2 fa = __half22float2(__builtin_bit_cast(__half2, qa.x));
        float2 fb = __half22float2(__builtin_bit_cast(__half2, qa.y));
        float2 fc = __half22float2(__builtin_bit_cast(__half2, qb.x));
        float2 fd = __half22float2(__builtin_bit_cast(__half2, qb.y));
        a0 += fa.x + fc.x;
        a1 += fa.y + fc.y;
        a2 += fb.x + fd.x;
        a3 += fb.y + fd.y;
    }
    if (i < seg1) {
        uint2 qa = y2[slist[i] * 4 + q];
        float2 fa = __half22float2(__builtin_bit_cast(__half2, qa.x));
        float2 fb = __half22float2(__builtin_bit_cast(__half2, qa.y));
        a0 += fa.x; a1 += fa.y; a2 += fb.x; a3 += fb.y;
    }

    // pass 5: fused epilogue. 4 classes per lane + width-4 shfl reductions.
    const float4 sf = ((const float4*)(outv + (size_t)n * NC))[q];
    float inv = 1.0f / fmaxf((float)deg, 1.0f);
    float v0 = a0 * inv + sb[4 * q + 0] + sf.x;
    float v1 = a1 * inv + sb[4 * q + 1] + sf.y;
    float v2 = a2 * inv + sb[4 * q + 2] + sf.z;
    float v3 = a3 * inv + sb[4 * q + 3] + sf.w;

    float m = fmaxf(fmaxf(v0, v1), fmaxf(v2, v3));
    m = fmaxf(m, __shfl_xor(m, 1, 4));
    m = fmaxf(m, __shfl_xor(m, 2, 4));
    float es = expf(v0 - m) + expf(v1 - m) + expf(v2 - m) + expf(v3 - m);
    es += __shfl_xor(es, 1, 4);
    es += __shfl_xor(es, 2, 4);
    float lse = m + logf(es);

    ((float4*)(outv + (size_t)n * NC))[q] = make_float4(v0, v1, v2, v3);
    ((float4*)(logp + (size_t)n * NC))[q] =
        make_float4(v0 - lse, v1 - lse, v2 - lse, v3 - lse);
}

extern "C" void kernel_launch(void* const* d_in, const int* in_sizes, int n_in,
                              void* d_out, int out_size, void* d_ws, size_t ws_size,
                              hipStream_t stream) {
    const float* x   = (const float*)d_in[0];
    const int*   ei  = (const int*)d_in[1];
    const float* W_l = (const float*)d_in[2];
    const float* b_l = (const float*)d_in[3];
    const float* W_r = (const float*)d_in[4];

    float* logp = (float*)d_out;                    // [NN*NC]
    float* outv = (float*)d_out + (size_t)NN * NC;  // [NN*NC], self scratch

    // ws: y_l half2[NN*8] (3.2MB) | buf u32[NE] (6.4MB) | counts_s[NB*16] | gcur_s[NB*16]
    __half2* y_l  = (__half2*)d_ws;
    unsigned* buf = (unsigned*)(y_l + (size_t)NN * 8);
    int* counts_s = (int*)(buf + NE);
    int* gcur_s   = counts_s + NB * 16;

    hipMemsetAsync(counts_s, 0, (size_t)NB * 16 * sizeof(int), stream);

    lin_kernel<<<1024, 256, 0, stream>>>(x, W_l, W_r, y_l, outv);
    hist_kernel<<<NBLK_PART, 256, 0, stream>>>(ei, counts_s);
    scan_kernel<<<1, 1024, 0, stream>>>(counts_s, gcur_s);
    place_kernel<<<NBLK_PART, 256, 0, stream>>>(ei, gcur_s, buf);
    agg_kernel<<<NB, 256, 0, stream>>>(counts_s, buf, (const uint2*)y_l, b_l, logp, outv);
}

// Round 7
// 155.052 us; speedup vs baseline: 2.0987x; 1.1828x over previous
//
#include <hip/hip_runtime.h>
#include <hip/hip_fp16.h>
#include <math.h>

#define NN 100000
#define NE 1600000
#define FIN 50
#define NC 16
#define TILE_NODES 32

#define NPB 256                       // nodes per bucket
#define NB  ((NN + NPB - 1) / NPB)    // 391 buckets
#define CAP 4608                      // slots per bucket region (mean 4092 + 8 sigma)
#define NBLK_PART 256
#define EPB ((NE + NBLK_PART - 1) / NBLK_PART)   // 6250 edges / partition block
#define NPS 64                        // nodes per agg sub-block
#define SLCAP 2048                    // slist cap per sub-block (mean 1024 + 16 sigma)

// ---------------------------------------------------------------------------
// Kernel 1: y_l = x @ W_l^T (f16, ws), self = x @ W_r^T (f32, d_out high half)
// ---------------------------------------------------------------------------
__global__ __launch_bounds__(256) void lin_kernel(
    const float* __restrict__ x,
    const float* __restrict__ W_l,
    const float* __restrict__ W_r,
    __half2* __restrict__ y_l,        // [NN*8]
    float* __restrict__ self_out)     // [NN*NC]
{
    __shared__ float sWl[NC * FIN];
    __shared__ float sWr[NC * FIN];
    __shared__ float sx[TILE_NODES * FIN];

    const int tid = threadIdx.x;
    for (int i = tid; i < NC * FIN; i += 256) {
        sWl[i] = W_l[i];
        sWr[i] = W_r[i];
    }

    const int ntiles = (NN + TILE_NODES - 1) / TILE_NODES;
    const int ln = tid >> 3;
    const int cp = tid & 7;

    for (int tile = blockIdx.x; tile < ntiles; tile += gridDim.x) {
        __syncthreads();
        const int node0 = tile * TILE_NODES;
        for (int i = tid; i < TILE_NODES * FIN; i += 256) {
            int n = node0 + i / FIN;
            sx[i] = (n < NN) ? x[n * FIN + (i % FIN)] : 0.0f;
        }
        __syncthreads();

        const int n = node0 + ln;
        if (n >= NN) continue;

        const float* xr = &sx[ln * FIN];
        const float* w0 = &sWl[(2 * cp) * FIN];
        const float* w1 = w0 + FIN;
        const float* u0 = &sWr[(2 * cp) * FIN];
        const float* u1 = u0 + FIN;

        float a0 = 0.f, a1 = 0.f, r0 = 0.f, r1 = 0.f;
#pragma unroll
        for (int k = 0; k < FIN; ++k) {
            float xv = xr[k];
            a0 = fmaf(xv, w0[k], a0);
            a1 = fmaf(xv, w1[k], a1);
            r0 = fmaf(xv, u0[k], r0);
            r1 = fmaf(xv, u1[k], r1);
        }
        y_l[n * 8 + cp] = __floats2half2_rn(a0, a1);
        ((float2*)self_out)[n * 8 + cp] = make_float2(r0, r1);
    }
}

// ---------------------------------------------------------------------------
// Kernel 2: placement into fixed-capacity bucket regions. No pre-pass needed:
// per-block LDS histogram -> one global cursor atomic per (block,bucket)
// reserves a contiguous chunk (avg 16 edges = one full 64B line) inside
// buf[b*CAP .. b*CAP+CAP). gcur_s[b*16] ends up holding the bucket count.
// Packed entry: src | (t&255)<<17.
// ---------------------------------------------------------------------------
__global__ __launch_bounds__(256) void place_kernel(
    const int* __restrict__ ei, int* __restrict__ gcur_s,
    unsigned int* __restrict__ buf)
{
    __shared__ int h[NB];
    __shared__ int cur[NB];
    const int tid = threadIdx.x;
    for (int i = tid; i < NB; i += 256) h[i] = 0;
    __syncthreads();
    int e0 = blockIdx.x * EPB;
    int e1 = min(e0 + EPB, NE);
    for (int e = e0 + tid; e < e1; e += 256)
        atomicAdd(&h[ei[NE + e] >> 8], 1);
    __syncthreads();
    for (int b = tid; b < NB; b += 256)
        cur[b] = h[b] ? atomicAdd(&gcur_s[b * 16], h[b]) : 0;
    __syncthreads();
    for (int e = e0 + tid; e < e1; e += 256) {
        int s = ei[e];
        int t = ei[NE + e];
        int b = t >> 8;
        int pos = atomicAdd(&cur[b], 1);
        if (pos < CAP)
            buf[(size_t)b * CAP + pos] = (unsigned)s | ((unsigned)(t & 255) << 17);
    }
}

// ---------------------------------------------------------------------------
// Kernel 3: aggregation. Grid = NB*4; sub-block j of bucket b handles the
// 64-node range [b*256+64j, +64). Filters the bucket list, counting-sorts it
// in LDS (int atomics only), then contention-free register segment-reduce +
// fused mean/bias/self/log_softmax epilogue (R6-proven structure).
// ---------------------------------------------------------------------------
__global__ __launch_bounds__(256) void agg_kernel(
    const int* __restrict__ gcur_s,
    const unsigned int* __restrict__ buf,
    const uint2* __restrict__ y2,     // y_l as uint2[NN*4]
    const float* __restrict__ b_l,
    float* __restrict__ logp,
    float* __restrict__ outv)         // self (f32) on entry, final out on exit
{
    __shared__ unsigned slist[SLCAP];
    __shared__ int lcnt[NPS];
    __shared__ int scur[NPS];
    __shared__ int sstart[NPS];
    __shared__ float sb[NC];

    const int tid = threadIdx.x;
    if (tid < NPS) lcnt[tid] = 0;
    if (tid < NC) sb[tid] = b_l[tid];
    __syncthreads();

    const int b = blockIdx.x >> 2;
    const int j = blockIdx.x & 3;
    int cnt = gcur_s[b * 16];
    if (cnt > CAP) cnt = CAP;
    const size_t base = (size_t)b * CAP;
    const unsigned lo = (unsigned)(j * NPS);

    // pass 1: filtered per-local-node counts
    for (int i = tid; i < cnt; i += 256) {
        unsigned tl = buf[base + i] >> 17;
        if ((tl >> 6) == (unsigned)j) atomicAdd(&lcnt[tl & 63], 1);
    }
    __syncthreads();

    // pass 2: 64-wide exclusive scan in the first wave
    if (tid < 64) {
        int own = lcnt[tid];
        int incl = own;
#pragma unroll
        for (int off = 1; off < 64; off <<= 1) {
            int t = __shfl_up(incl, off, 64);
            if (tid >= off) incl += t;
        }
        sstart[tid] = incl - own;
        scur[tid]   = incl - own;
    }
    __syncthreads();

    // pass 3: filtered scatter of src ids into sorted slots
    for (int i = tid; i < cnt; i += 256) {
        unsigned v = buf[base + i];
        unsigned tl = v >> 17;
        if ((tl >> 6) == (unsigned)j) {
            int pos = atomicAdd(&scur[tl & 63], 1);
            if (pos < SLCAP) slist[pos] = v & 0x1FFFF;
        }
    }
    __syncthreads();

    // pass 4: segment reduce, registers only. tid = tl*4 + q.
    const int tl = tid >> 2;
    const int q  = tid & 3;
    const int n  = b * NPB + j * NPS + tl;
    if (n >= NN) return;

    const int seg0 = sstart[tl];
    const int deg  = lcnt[tl];
    int seg1 = seg0 + deg;
    if (seg1 > SLCAP) seg1 = SLCAP;

    float a0 = 0.f, a1 = 0.f, a2 = 0.f, a3 = 0.f;
    int i = seg0;
    for (; i + 2 <= seg1; i += 2) {
        int sA = slist[i];
        int sB = slist[i + 1];
        uint2 qa = y2[sA * 4 + q];
        uint2 qb = y2[sB * 4 + q];
        float2 fa = __half22float2(__builtin_bit_cast(__half2, qa.x));
        float2 fb = __half22float2(__builtin_bit_cast(__half2, qa.y));
        float2 fc = __half22float2(__builtin_bit_cast(__half2, qb.x));
        float2 fd = __half22float2(__builtin_bit_cast(__half2, qb.y));
        a0 += fa.x + fc.x;
        a1 += fa.y + fc.y;
        a2 += fb.x + fd.x;
        a3 += fb.y + fd.y;
    }
    if (i < seg1) {
        uint2 qa = y2[slist[i] * 4 + q];
        float2 fa = __half22float2(__builtin_bit_cast(__half2, qa.x));
        float2 fb = __half22float2(__builtin_bit_cast(__half2, qa.y));
        a0 += fa.x; a1 += fa.y; a2 += fb.x; a3 += fb.y;
    }

    // pass 5: fused epilogue, width-4 shfl reductions
    const float4 sf = ((const float4*)(outv + (size_t)n * NC))[q];
    float inv = 1.0f / fmaxf((float)deg, 1.0f);
    float v0 = a0 * inv + sb[4 * q + 0] + sf.x;
    float v1 = a1 * inv + sb[4 * q + 1] + sf.y;
    float v2 = a2 * inv + sb[4 * q + 2] + sf.z;
    float v3 = a3 * inv + sb[4 * q + 3] + sf.w;

    float m = fmaxf(fmaxf(v0, v1), fmaxf(v2, v3));
    m = fmaxf(m, __shfl_xor(m, 1, 4));
    m = fmaxf(m, __shfl_xor(m, 2, 4));
    float es = expf(v0 - m) + expf(v1 - m) + expf(v2 - m) + expf(v3 - m);
    es += __shfl_xor(es, 1, 4);
    es += __shfl_xor(es, 2, 4);
    float lse = m + logf(es);

    ((float4*)(outv + (size_t)n * NC))[q] = make_float4(v0, v1, v2, v3);
    ((float4*)(logp + (size_t)n * NC))[q] =
        make_float4(v0 - lse, v1 - lse, v2 - lse, v3 - lse);
}

extern "C" void kernel_launch(void* const* d_in, const int* in_sizes, int n_in,
                              void* d_out, int out_size, void* d_ws, size_t ws_size,
                              hipStream_t stream) {
    const float* x   = (const float*)d_in[0];
    const int*   ei  = (const int*)d_in[1];
    const float* W_l = (const float*)d_in[2];
    const float* b_l = (const float*)d_in[3];
    const float* W_r = (const float*)d_in[4];

    float* logp = (float*)d_out;                    // [NN*NC]
    float* outv = (float*)d_out + (size_t)NN * NC;  // [NN*NC], self scratch

    // ws: y_l half2[NN*8] (3.2MB) | buf u32[NB*CAP] (7.2MB) | gcur_s[NB*16] (25KB)
    __half2* y_l  = (__half2*)d_ws;
    unsigned* buf = (unsigned*)(y_l + (size_t)NN * 8);
    int* gcur_s   = (int*)(buf + (size_t)NB * CAP);

    hipMemsetAsync(gcur_s, 0, (size_t)NB * 16 * sizeof(int), stream);

    lin_kernel<<<1024, 256, 0, stream>>>(x, W_l, W_r, y_l, outv);
    place_kernel<<<NBLK_PART, 256, 0, stream>>>(ei, gcur_s, buf);
    agg_kernel<<<NB * 4, 256, 0, stream>>>(gcur_s, buf, (const uint2*)y_l, b_l, logp, outv);
}

// Round 8
// 128.875 us; speedup vs baseline: 2.5250x; 1.2031x over previous
//
#include <hip/hip_runtime.h>
#include <hip/hip_fp16.h>
#include <math.h>

#define NN 100000
#define NE 1600000
#define FIN 50
#define NC 16
#define TILE_NODES 32

#define NPB 256                       // nodes per bucket
#define NB  ((NN + NPB - 1) / NPB)    // 391 buckets
#define CAP 4608                      // slots per bucket region (mean 4092 + 8 sigma)
#define NBLK_PART 256
#define EPB ((NE + NBLK_PART - 1) / NBLK_PART)   // 6250 edges / partition block
#define NBLK_LIN 1024

// ---------------------------------------------------------------------------
// Fused front-end. Blocks [0, NBLK_PART): placement of edges into
// fixed-capacity bucket regions (latency-bound fabric scatter). Blocks
// [NBLK_PART, NBLK_PART+NBLK_LIN): y_l = x@W_l^T (f16) and self = x@W_r^T
// (f32) (LDS/VALU-bound). Independent work, disjoint resources -> overlap:
// cost = max, not sum. Branch is block-uniform (no divergence).
// ---------------------------------------------------------------------------
__global__ __launch_bounds__(256) void fused_front(
    const float* __restrict__ x,
    const float* __restrict__ W_l,
    const float* __restrict__ W_r,
    const int* __restrict__ ei,       // [2, NE]
    int* __restrict__ gcur_s,         // [NB*16] cursors (zeroed)
    unsigned int* __restrict__ buf,   // [NB*CAP]
    __half2* __restrict__ y_l,        // [NN*8]
    float* __restrict__ self_out)     // [NN*NC]
{
    __shared__ __align__(16) char smem[12800];
    const int tid = threadIdx.x;

    if (blockIdx.x < NBLK_PART) {
        // ---- place role ----
        int* h   = (int*)smem;        // [NB]
        int* cur = h + NB;            // [NB]
        for (int i = tid; i < NB; i += 256) h[i] = 0;
        __syncthreads();
        int e0 = blockIdx.x * EPB;
        int e1 = min(e0 + EPB, NE);
        for (int e = e0 + tid; e < e1; e += 256)
            atomicAdd(&h[ei[NE + e] >> 8], 1);
        __syncthreads();
        for (int b = tid; b < NB; b += 256)
            cur[b] = h[b] ? atomicAdd(&gcur_s[b * 16], h[b]) : 0;
        __syncthreads();
        for (int e = e0 + tid; e < e1; e += 256) {
            int s = ei[e];
            int t = ei[NE + e];
            int b = t >> 8;
            int pos = atomicAdd(&cur[b], 1);
            if (pos < CAP)
                buf[(size_t)b * CAP + pos] = (unsigned)s | ((unsigned)(t & 255) << 17);
        }
    } else {
        // ---- lin role ----
        float* sWl = (float*)smem;            // [NC*FIN]
        float* sWr = sWl + NC * FIN;          // [NC*FIN]
        float* sx  = sWr + NC * FIN;          // [TILE_NODES*FIN]

        for (int i = tid; i < NC * FIN; i += 256) {
            sWl[i] = W_l[i];
            sWr[i] = W_r[i];
        }

        const int bidx = blockIdx.x - NBLK_PART;
        const int ntiles = (NN + TILE_NODES - 1) / TILE_NODES;
        const int ln = tid >> 3;
        const int cp = tid & 7;

        for (int tile = bidx; tile < ntiles; tile += NBLK_LIN) {
            __syncthreads();
            const int node0 = tile * TILE_NODES;
            for (int i = tid; i < TILE_NODES * FIN; i += 256) {
                int n = node0 + i / FIN;
                sx[i] = (n < NN) ? x[n * FIN + (i % FIN)] : 0.0f;
            }
            __syncthreads();

            const int n = node0 + ln;
            if (n >= NN) continue;

            const float* xr = &sx[ln * FIN];
            const float* w0 = &sWl[(2 * cp) * FIN];
            const float* w1 = w0 + FIN;
            const float* u0 = &sWr[(2 * cp) * FIN];
            const float* u1 = u0 + FIN;

            float a0 = 0.f, a1 = 0.f, r0 = 0.f, r1 = 0.f;
#pragma unroll
            for (int k = 0; k < FIN; ++k) {
                float xv = xr[k];
                a0 = fmaf(xv, w0[k], a0);
                a1 = fmaf(xv, w1[k], a1);
                r0 = fmaf(xv, u0[k], r0);
                r1 = fmaf(xv, u1[k], r1);
            }
            y_l[n * 8 + cp] = __floats2half2_rn(a0, a1);
            ((float2*)self_out)[n * 8 + cp] = make_float2(r0, r1);
        }
    }
}

// ---------------------------------------------------------------------------
// Aggregation: one 1024-thread block per bucket (256 nodes). In-LDS counting
// sort by local target (int atomics only), 256-wide scan (wave-scan + wave
// sums), contention-free register segment-reduce (tid = tl*4+q, quad covers
// 16 classes via uint2 loads), fused mean/bias/self/log_softmax epilogue.
// ---------------------------------------------------------------------------
__global__ __launch_bounds__(1024) void agg_kernel(
    const int* __restrict__ gcur_s,
    const unsigned int* __restrict__ buf,
    const uint2* __restrict__ y2,     // y_l as uint2[NN*4]
    const float* __restrict__ b_l,
    float* __restrict__ logp,
    float* __restrict__ outv)         // self (f32) on entry, final out on exit
{
    __shared__ unsigned slist[CAP];   // 18.4 KB
    __shared__ int lcnt[NPB];
    __shared__ int scur[NPB];
    __shared__ int sstart[NPB];
    __shared__ int wsum[4];
    __shared__ float sb[NC];

    const int tid = threadIdx.x;
    if (tid < NPB) lcnt[tid] = 0;
    if (tid < NC) sb[tid] = b_l[tid];
    __syncthreads();

    const int b = blockIdx.x;
    int cnt = gcur_s[b * 16];
    if (cnt > CAP) cnt = CAP;
    const size_t base = (size_t)b * CAP;

    // pass 1: per-local-node counts (1 LDS int atomic per edge)
    for (int i = tid; i < cnt; i += 1024)
        atomicAdd(&lcnt[buf[base + i] >> 17], 1);
    __syncthreads();

    // pass 2: 256-wide exclusive scan (4 waves scan 64 each, then fixup)
    int own = 0, incl = 0;
    if (tid < NPB) {
        own = lcnt[tid];
        incl = own;
#pragma unroll
        for (int off = 1; off < 64; off <<= 1) {
            int t = __shfl_up(incl, off, 64);
            if ((tid & 63) >= off) incl += t;
        }
        if ((tid & 63) == 63) wsum[tid >> 6] = incl;
    }
    __syncthreads();
    if (tid < NPB) {
        const int w = tid >> 6;
        int pfx = 0;
        if (w > 0) pfx += wsum[0];
        if (w > 1) pfx += wsum[1];
        if (w > 2) pfx += wsum[2];
        const int st = pfx + incl - own;
        sstart[tid] = st;
        scur[tid]   = st;
    }
    __syncthreads();

    // pass 3: scatter src ids into sorted slots (1 atomic + 1 write per edge)
    for (int i = tid; i < cnt; i += 1024) {
        unsigned v = buf[base + i];
        int pos = atomicAdd(&scur[v >> 17], 1);
        slist[pos] = v & 0x1FFFF;
    }
    __syncthreads();

    // pass 4: segment reduce, registers only. tid = tl*4 + q.
    const int tl = tid >> 2;
    const int q  = tid & 3;
    const int n  = b * NPB + tl;
    if (n >= NN) return;

    const int seg0 = sstart[tl];
    const int deg  = lcnt[tl];
    const int seg1 = seg0 + deg;

    float a0 = 0.f, a1 = 0.f, a2 = 0.f, a3 = 0.f;
    int i = seg0;
    for (; i + 2 <= seg1; i += 2) {
        int sA = slist[i];
        int sB = slist[i + 1];
        uint2 qa = y2[sA * 4 + q];
        uint2 qb = y2[sB * 4 + q];
        float2 fa = __half22float2(__builtin_bit_cast(__half2, qa.x));
        float2 fb = __half22float2(__builtin_bit_cast(__half2, qa.y));
        float2 fc = __half22float2(__builtin_bit_cast(__half2, qb.x));
        float2 fd = __half22float2(__builtin_bit_cast(__half2, qb.y));
        a0 += fa.x + fc.x;
        a1 += fa.y + fc.y;
        a2 += fb.x + fd.x;
        a3 += fb.y + fd.y;
    }
    if (i < seg1) {
        uint2 qa = y2[slist[i] * 4 + q];
        float2 fa = __half22float2(__builtin_bit_cast(__half2, qa.x));
        float2 fb = __half22float2(__builtin_bit_cast(__half2, qa.y));
        a0 += fa.x; a1 += fa.y; a2 += fb.x; a3 += fb.y;
    }

    // pass 5: fused epilogue, width-4 shfl reductions
    const float4 sf = ((const float4*)(outv + (size_t)n * NC))[q];
    float inv = 1.0f / fmaxf((float)deg, 1.0f);
    float v0 = a0 * inv + sb[4 * q + 0] + sf.x;
    float v1 = a1 * inv + sb[4 * q + 1] + sf.y;
    float v2 = a2 * inv + sb[4 * q + 2] + sf.z;
    float v3 = a3 * inv + sb[4 * q + 3] + sf.w;

    float m = fmaxf(fmaxf(v0, v1), fmaxf(v2, v3));
    m = fmaxf(m, __shfl_xor(m, 1, 4));
    m = fmaxf(m, __shfl_xor(m, 2, 4));
    float es = expf(v0 - m) + expf(v1 - m) + expf(v2 - m) + expf(v3 - m);
    es += __shfl_xor(es, 1, 4);
    es += __shfl_xor(es, 2, 4);
    float lse = m + logf(es);

    ((float4*)(outv + (size_t)n * NC))[q] = make_float4(v0, v1, v2, v3);
    ((float4*)(logp + (size_t)n * NC))[q] =
        make_float4(v0 - lse, v1 - lse, v2 - lse, v3 - lse);
}

extern "C" void kernel_launch(void* const* d_in, const int* in_sizes, int n_in,
                              void* d_out, int out_size, void* d_ws, size_t ws_size,
                              hipStream_t stream) {
    const float* x   = (const float*)d_in[0];
    const int*   ei  = (const int*)d_in[1];
    const float* W_l = (const float*)d_in[2];
    const float* b_l = (const float*)d_in[3];
    const float* W_r = (const float*)d_in[4];

    float* logp = (float*)d_out;                    // [NN*NC]
    float* outv = (float*)d_out + (size_t)NN * NC;  // [NN*NC], self scratch

    // ws: y_l half2[NN*8] (3.2MB) | buf u32[NB*CAP] (7.2MB) | gcur_s[NB*16] (25KB)
    __half2* y_l  = (__half2*)d_ws;
    unsigned* buf = (unsigned*)(y_l + (size_t)NN * 8);
    int* gcur_s   = (int*)(buf + (size_t)NB * CAP);

    hipMemsetAsync(gcur_s, 0, (size_t)NB * 16 * sizeof(int), stream);

    fused_front<<<NBLK_PART + NBLK_LIN, 256, 0, stream>>>(
        x, W_l, W_r, ei, gcur_s, buf, y_l, outv);
    agg_kernel<<<NB, 1024, 0, stream>>>(gcur_s, buf, (const uint2*)y_l, b_l, logp, outv);
}